// Round 7
// baseline (483.403 us; speedup 1.0000x reference)
//
#include <hip/hip_runtime.h>
#include <hip/hip_bf16.h>

typedef _Float16 f16;
typedef _Float16 f16x2 __attribute__((ext_vector_type(2)));
typedef _Float16 f16x4 __attribute__((ext_vector_type(4)));
typedef _Float16 f16x8 __attribute__((ext_vector_type(8)));
typedef float f32x4 __attribute__((ext_vector_type(4)));

#define B_  4
#define L_  2048
#define D_  4096
#define H_  8
#define BW_ 512
#define M_  (B_*L_)      // 8192
#define CHUNK 128
#define NCH (L_/CHUNK)   // 16
#define NCHAINS 256      // bb(4) * h(8) * nb(8)
#define NITEMS  4096     // NCH * NCHAINS
#define LOG2E 1.4426950408889634f

// workspace layout (bytes)
static const size_t OFF_WPK   = 0;                 // packed B frags: 8MB (both gates)
static const size_t OFF_MSP   = 8ull<<20;          // D_ f32 (16KB), pre-scaled by log2e
static const size_t OFF_XH    = 9ull<<20;          // M*D fp16 = 64MB
static const size_t OFF_VALS  = 73ull<<20;         // NITEMS*64 u32 (h_end) = 1MB
static const size_t OFF_FLAGS = 74ull<<20;         // NITEMS u32 = 16KB
static const size_t OFF_CNT   = 75ull<<20;         // 1 u32 ticket counter

__device__ __forceinline__ void gl16(const void* g, void* l) {
    __builtin_amdgcn_global_load_lds(
        (const __attribute__((address_space(1))) unsigned int*)g,
        (__attribute__((address_space(3))) unsigned int*)l, 16, 0, 0);
}

// ---------- prep: pack W^T into MFMA B-fragment order, f32 -> f16 ----------
// layout: wpk[((h*16 + n32)*8 + kt)*8 + fidx][lane] : f16x8
//   fidx = g*4 + fn*2 + kk2 ; fragment element e:
//   B[n = n32*32 + fn*16 + (lane&15)][k = kt*64 + kk2*32 + (lane>>4)*8 + e]
//   where B[n][k] = w[h][k][n]
__global__ __launch_bounds__(256)
void prep_wpack(const float* __restrict__ w_in, const float* __restrict__ w_a,
                f16* __restrict__ wpk) {
    const int kt  = blockIdx.x & 7;
    const int n32 = (blockIdx.x >> 3) & 15;
    const int h   = blockIdx.x >> 7;
    const int tid = threadIdx.x;
#pragma unroll
    for (int q = 0; q < 2; ++q) {
        int slot = q * 256 + tid;          // 0..511
        int lane = slot & 63;
        int fidx = slot >> 6;              // g*4 + fn*2 + kk2
        int g    = fidx >> 2;
        int fn   = (fidx >> 1) & 1;
        int kk2  = fidx & 1;
        int row = n32 * 32 + fn * 16 + (lane & 15);
        int col = kt * 64 + kk2 * 32 + ((lane >> 4) << 3);
        const float* src = (g ? w_a : w_in) + (size_t)h * BW_ * BW_;
        f16x8 v;
#pragma unroll
        for (int e = 0; e < 8; ++e)
            v[e] = (f16)src[(size_t)(col + e) * BW_ + row];
        size_t o = ((((size_t)(h * 16 + n32) * 8 + kt) * 8) + fidx) * 64 + lane;
        *(f16x8*)(wpk + o * 8) = v;
    }
}

// ---------- prep: msp2[d] = -8 * softplus(a_param[d]) * log2(e) ----------
__global__ __launch_bounds__(256)
void prep_msp(const float* __restrict__ a_param, float* __restrict__ msp2) {
    int d = blockIdx.x * 256 + threadIdx.x;
    float v = a_param[d];
    msp2[d] = -8.f * log1pf(expf(v)) * LOG2E;
}

// ---------- prep: x -> fp16 ----------
__global__ __launch_bounds__(256)
void prep_xh(const float* __restrict__ x, f16* __restrict__ xh) {
    size_t i = ((size_t)blockIdx.x * 256 + threadIdx.x) * 8;
    size_t stride = (size_t)gridDim.x * 256 * 8;
    for (; i < (size_t)M_ * D_; i += stride) {
        f32x4 v0 = *(const f32x4*)(x + i);
        f32x4 v1 = *(const f32x4*)(x + i + 4);
        f16x8 hv;
        hv[0] = (f16)v0.x; hv[1] = (f16)v0.y; hv[2] = (f16)v0.z; hv[3] = (f16)v0.w;
        hv[4] = (f16)v1.x; hv[5] = (f16)v1.y; hv[6] = (f16)v1.z; hv[7] = (f16)v1.w;
        *(f16x8*)(xh + i) = hv;
    }
}

// ---------- prep: zero chain flags + ticket counter (every launch) ----------
__global__ __launch_bounds__(256)
void zero_sync(unsigned* __restrict__ flags, unsigned* __restrict__ counter) {
    int i = blockIdx.x * 256 + threadIdx.x;
    if (i < NITEMS) flags[i] = 0u;
    if (i == 0) *counter = 0u;
}

// ---------- persistent fused GEMM + epilogue + chained scan ----------
// BM=128 (= one scan chunk), BN=64, 4 waves (2x2), mfma 16x16x32 f16.
// A via global_load_lds dbuf; B via pre-packed register fragments.
// Items claimed chunk-major via atomic tickets: item = cc*256 + chain;
// predecessor (item-256) always claimed earlier -> deadlock-free look-back.
#define BM 128
#define BN 64
#define BKK 64
#define NT (BW_/BKK)     // 8 K-tiles
#define BUFB 16384       // bytes per A staging buffer

// LDS map: staging buf0 @0, buf1 @16384.  Post-K-loop overlay:
//  a_s[128][65]f32 @0 | xn_s[128][66]f16 @33280 | segA[4][72] @50176 |
//  segY[4][72] @51328 | rst_s[128] @52480 | h0_s[64] @52992 | tkt @53248
#define SMEM_BYTES 53504

__global__ __launch_bounds__(256, 3)
void gemm_chain(const f16*   __restrict__ xh,
                const int*   __restrict__ segpos,
                const f16*   __restrict__ wpk,
                const float* __restrict__ b_in,
                const float* __restrict__ b_a,
                const float* __restrict__ msp2,
                unsigned* __restrict__ vals,
                unsigned* __restrict__ flags,
                unsigned* __restrict__ counter,
                float* __restrict__ y) {
    __shared__ __align__(16) char smem[SMEM_BYTES];
    float*    a_s   = (float*)smem;               // [128][65]
    f16*      xn_s  = (f16*)(smem + 33280);       // [128][66]
    float*    segA  = (float*)(smem + 50176);     // [4][72]
    float*    segY  = (float*)(smem + 51328);     // [4][72]
    float*    rst_s = (float*)(smem + 52480);     // [128]
    float*    h0_s  = (float*)(smem + 52992);     // [64]
    unsigned* tkt_s = (unsigned*)(smem + 53248);

    const int tid  = threadIdx.x;
    const int lane = tid & 63;
    const int wid  = tid >> 6;
    const int wr   = wid >> 1;
    const int wc   = wid & 1;

    const int grow  = lane >> 3;
    const int gcolS = (((lane & 7) ^ grow) << 3);
    const int swz   = (lane & 7) << 3;       // read-side XOR (involution)
    const int kx    = (lane >> 4) << 3;      // 0,8,16,24
    const int arow  = wr * 64 + (lane & 15);
    const int rowb  = wr * 64 + ((lane >> 4) << 2);
    const int scol  = tid & 63;
    const int sseg  = tid >> 6;

    for (;;) {
        if (tid == 0) *tkt_s = atomicAdd(counter, 1u);
        __syncthreads();                      // tkt visible; prev item's LDS reads done
        const unsigned item = *tkt_s;
        if (item >= NITEMS) break;
        const int cc    = item >> 8;          // chunk in batch 0..15
        const int chain = item & 255;
        const int bb    = chain >> 6;
        const int h     = (chain >> 3) & 7;
        const int nb    = chain & 7;
        const int m0    = bb * L_ + cc * CHUNK;
        const int n0    = nb * 64;

        f32x4 accX[4][2] = {};
        f32x4 accA[4][2] = {};

        if (tid < BM) rst_s[tid] = (segpos[m0 + tid] == 0) ? 1.f : 0.f;

        const f16* aSrc  = xh + (size_t)(m0 + wid * 32 + grow) * D_ + h * BW_ + gcolS;
        const f16* wbase = wpk + ((size_t)(h * 16) + (n0 >> 5) + wc) * 32768;
        const int  txo   = (n0 >> 6) + 1;     // permutation: tile (n0>>6) goes last

        f16x8 bfr[2][8];

        // prologue: stage permuted tile 0 (A -> buf0, B -> bfr[0])
        {
            const int k0 = (txo & (NT - 1)) * BKK;
            f16* Asb = (f16*)smem;
#pragma unroll
            for (int q = 0; q < 4; ++q)
                gl16(aSrc + k0 + (size_t)q * 8 * D_, &Asb[(wid * 32 + q * 8) * 64]);
            const f16* tp = wbase + (size_t)(txo & (NT - 1)) * 4096;
#pragma unroll
            for (int j = 0; j < 8; ++j)
                bfr[0][j] = *(const f16x8*)(tp + j * 512 + lane * 8);
        }

#pragma unroll
        for (int t = 0; t < NT; ++t) {
            const int cur = t & 1;
            if (t + 1 < NT) {
                const int kt1 = (t + 1 + txo) & (NT - 1);
                f16* Asb = (f16*)(smem + (cur ^ 1) * BUFB);
#pragma unroll
                for (int q = 0; q < 4; ++q)
                    gl16(aSrc + kt1 * BKK + (size_t)q * 8 * D_, &Asb[(wid * 32 + q * 8) * 64]);
                const f16* tp = wbase + (size_t)kt1 * 4096;
#pragma unroll
                for (int j = 0; j < 8; ++j)
                    bfr[cur ^ 1][j] = *(const f16x8*)(tp + j * 512 + lane * 8);
                asm volatile("s_waitcnt vmcnt(12)" ::: "memory");  // tile t landed
            } else {
                asm volatile("s_waitcnt vmcnt(0)" ::: "memory");
            }
            __builtin_amdgcn_s_barrier();
            __builtin_amdgcn_sched_barrier(0);

            const f16* Asb = (const f16*)(smem + cur * BUFB);
#pragma unroll
            for (int kk2 = 0; kk2 < 2; ++kk2) {
                const int kcolS = (kk2 * 32 + kx) ^ swz;
                f16x8 af[4];
#pragma unroll
                for (int fm = 0; fm < 4; ++fm)
                    af[fm] = *(const f16x8*)&Asb[(arow + fm * 16) * 64 + kcolS];
#pragma unroll
                for (int fn = 0; fn < 2; ++fn) {
                    f16x8 bx = bfr[cur][fn * 2 + kk2];
                    f16x8 ba = bfr[cur][4 + fn * 2 + kk2];
#pragma unroll
                    for (int fm = 0; fm < 4; ++fm) {
                        accX[fm][fn] = __builtin_amdgcn_mfma_f32_16x16x32_f16(af[fm], bx, accX[fm][fn], 0, 0, 0);
                        accA[fm][fn] = __builtin_amdgcn_mfma_f32_16x16x32_f16(af[fm], ba, accA[fm][fn], 0, 0, 0);
                    }
                }
            }
            __builtin_amdgcn_sched_barrier(0);
            __builtin_amdgcn_s_barrier();
        }

        // ---- xv harvest: last tile (buf1) holds A cols [n0,n0+64) ----
        const f16* As1 = (const f16*)(smem + BUFB);
        f16 xvv[2][4][4];
#pragma unroll
        for (int fn = 0; fn < 2; ++fn) {
            const int ctile = wc * 32 + fn * 16 + (lane & 15);
#pragma unroll
            for (int fm = 0; fm < 4; ++fm)
#pragma unroll
                for (int reg = 0; reg < 4; ++reg) {
                    const int rowt = rowb + fm * 16 + reg;
                    xvv[fn][fm][reg] = As1[rowt * 64 + (ctile ^ ((rowt & 7) << 3))];
                }
        }
        __syncthreads();   // xv in regs before overlay writes

        // ---- pass A: epilogue math -> a (f32) + xn (f16) in LDS ----
        // C/D layout: col = lane&15, row = (lane>>4)*4 + reg  [m89-verified]
#pragma unroll
        for (int fn = 0; fn < 2; ++fn) {
            const int ctile = wc * 32 + fn * 16 + (lane & 15);
            const int d = h * BW_ + n0 + ctile;
            const float bx = b_in[d];
            const float ba = b_a[d];
            const float mspd = msp2[d];
#pragma unroll
            for (int fm = 0; fm < 4; ++fm) {
#pragma unroll
                for (int reg = 0; reg < 4; ++reg) {
                    const int rowt = rowb + fm * 16 + reg;       // 0..127
                    float gxl = accX[fm][fn][reg] + bx;
                    float gal = accA[fm][fn][reg] + ba;
                    float gx = __builtin_amdgcn_rcpf(1.f + __builtin_amdgcn_exp2f(-gxl * LOG2E));
                    float ga = __builtin_amdgcn_rcpf(1.f + __builtin_amdgcn_exp2f(-gal * LOG2E));
                    float a  = __builtin_amdgcn_exp2f(mspd * ga);
                    float a2 = a * a;                            // = exp(2*log_a)
                    float mult = __builtin_amdgcn_sqrtf(1.f + 1e-6f - a2);
                    float rv = rst_s[rowt];
                    a *= (1.f - rv);
                    mult = rv + (1.f - rv) * mult;
                    float xv = (float)xvv[fn][fm][reg];
                    a_s[rowt * 65 + ctile] = a;
                    xn_s[rowt * 66 + ctile] = (f16)(xv * gx * mult);
                }
            }
        }
        __syncthreads();

        // ---- pass B: per-segment (32-step) local summaries ----
        {
            float A = 1.f, yv = 0.f;
#pragma unroll 4
            for (int t = sseg * 32; t < sseg * 32 + 32; ++t) {
                float a  = a_s[t * 65 + scol];
                float xn = (float)xn_s[t * 66 + scol];
                yv = fmaf(a, yv, xn);
                A *= a;
            }
            segA[sseg * 72 + scol] = A;
            segY[sseg * 72 + scol] = yv;
        }
        __syncthreads();

        // ---- look-back: receive h0 from predecessor chunk, publish h_end ----
        if (tid < 64) {
            float Af = 1.f, ye = 0.f;
#pragma unroll
            for (int s = 0; s < 4; ++s) {
                float As_ = segA[s * 72 + tid];
                ye = fmaf(As_, ye, segY[s * 72 + tid]);
                Af *= As_;
            }
            float h0 = 0.f;
            if (cc > 0) {
                const unsigned* flg = flags + (item - NCHAINS);
                while (__hip_atomic_load(flg, __ATOMIC_ACQUIRE,
                                         __HIP_MEMORY_SCOPE_AGENT) == 0u)
                    __builtin_amdgcn_s_sleep(2);
                unsigned hv = __hip_atomic_load(
                    vals + (size_t)(item - NCHAINS) * 64 + tid,
                    __ATOMIC_RELAXED, __HIP_MEMORY_SCOPE_AGENT);
                h0 = __uint_as_float(hv);
            }
            h0_s[tid] = h0;
            float hend = fmaf(Af, h0, ye);
            __hip_atomic_store(vals + (size_t)item * 64 + tid,
                               __float_as_uint(hend),
                               __ATOMIC_RELAXED, __HIP_MEMORY_SCOPE_AGENT);
            asm volatile("s_waitcnt vmcnt(0)" ::: "memory");
            __threadfence();
            if (tid == 0)
                __hip_atomic_store(flags + item, 1u,
                                   __ATOMIC_RELEASE, __HIP_MEMORY_SCOPE_AGENT);
        }
        __syncthreads();

        // ---- pass C: final scan walk, write y (f32) directly ----
        {
            float cy = h0_s[scol];
            for (int s = 0; s < sseg; ++s)
                cy = fmaf(segA[s * 72 + scol], cy, segY[s * 72 + scol]);
            float yv = cy;
            const size_t obase = (size_t)(m0 + sseg * 32) * D_ + h * BW_ + n0 + scol;
#pragma unroll 4
            for (int i = 0; i < 32; ++i) {
                const int t = sseg * 32 + i;
                float a  = a_s[t * 65 + scol];
                float xn = (float)xn_s[t * 66 + scol];
                yv = fmaf(a, yv, xn);
                y[obase + (size_t)i * D_] = yv;
            }
        }
        // loop: claim-barrier at top protects LDS reuse
    }
}

extern "C" void kernel_launch(void* const* d_in, const int* in_sizes, int n_in,
                              void* d_out, int out_size, void* d_ws, size_t ws_size,
                              hipStream_t stream) {
    const float* x       = (const float*)d_in[0];
    const int*   segpos  = (const int*)d_in[1];
    // d_in[2] = prev_h (unused by reference for L>1 path)
    const float* w_in    = (const float*)d_in[3];
    const float* b_in    = (const float*)d_in[4];
    const float* w_a     = (const float*)d_in[5];
    const float* b_a     = (const float*)d_in[6];
    const float* a_param = (const float*)d_in[7];

    float* y  = (float*)d_out;
    char*  ws = (char*)d_ws;
    f16*      wpk   = (f16*)(ws + OFF_WPK);
    float*    msp2  = (float*)(ws + OFF_MSP);
    f16*      xh    = (f16*)(ws + OFF_XH);
    unsigned* vals  = (unsigned*)(ws + OFF_VALS);
    unsigned* flags = (unsigned*)(ws + OFF_FLAGS);
    unsigned* cnt   = (unsigned*)(ws + OFF_CNT);

    prep_wpack<<<dim3(1024), 256, 0, stream>>>(w_in, w_a, wpk);
    prep_msp<<<dim3(D_ / 256), 256, 0, stream>>>(a_param, msp2);
    zero_sync<<<dim3(NITEMS / 256), 256, 0, stream>>>(flags, cnt);
    prep_xh<<<dim3(2048), 256, 0, stream>>>(x, xh);
    gemm_chain<<<dim3(768), 256, 0, stream>>>(
        xh, segpos, wpk, b_in, b_a, msp2, vals, flags, cnt, y);
}

// Round 8
// 447.326 us; speedup vs baseline: 1.0807x; 1.0807x over previous
//
#include <hip/hip_runtime.h>
#include <hip/hip_bf16.h>

typedef _Float16 f16;
typedef _Float16 f16x2 __attribute__((ext_vector_type(2)));
typedef _Float16 f16x4 __attribute__((ext_vector_type(4)));
typedef _Float16 f16x8 __attribute__((ext_vector_type(8)));
typedef float f32x4 __attribute__((ext_vector_type(4)));

#define B_  4
#define L_  2048
#define D_  4096
#define H_  8
#define BW_ 512
#define M_  (B_*L_)      // 8192
#define CHUNK 128
#define NCH (L_/CHUNK)   // 16
#define LOG2E 1.4426950408889634f

// workspace layout (bytes)
static const size_t OFF_WPK   = 0;                 // packed B frags: 8MB (both gates)
static const size_t OFF_MSP   = 8ull<<20;          // D_ f32 (16KB), pre-scaled by log2e
static const size_t OFF_XH    = 9ull<<20;          // M*D fp16 = 64MB
static const size_t OFF_YLAP  = 73ull<<20;         // M*D f16x2 (yloc,apfx) = 134MB
static const size_t OFF_SUMA  = 208ull<<20;        // B*NCH*D f32 = 1MB
static const size_t OFF_SUMY  = 209ull<<20;
static const size_t OFF_CARRY = 210ull<<20;

__device__ __forceinline__ void gl16(const void* g, void* l) {
    __builtin_amdgcn_global_load_lds(
        (const __attribute__((address_space(1))) unsigned int*)g,
        (__attribute__((address_space(3))) unsigned int*)l, 16, 0, 0);
}

// ---------- prep: pack W^T into MFMA B-fragment order (+ msp2) ----------
// layout: wpk[((h*16 + n32)*8 + kt)*8 + fidx][lane] : f16x8
//   fidx = g*4 + fn*2 + kk2 ; fragment element e:
//   B[n = n32*32 + fn*16 + (lane&15)][k = kt*64 + kk2*32 + (lane>>4)*8 + e]
//   where B[n][k] = w[h][k][n]
__global__ __launch_bounds__(256)
void prep_wpack(const float* __restrict__ w_in, const float* __restrict__ w_a,
                const float* __restrict__ a_param,
                f16* __restrict__ wpk, float* __restrict__ msp2) {
    const int kt  = blockIdx.x & 7;
    const int n32 = (blockIdx.x >> 3) & 15;
    const int h   = blockIdx.x >> 7;
    const int tid = threadIdx.x;
    if (blockIdx.x < 16) {                 // folded: msp2[d]
        int d = blockIdx.x * 256 + tid;
        float v = a_param[d];
        msp2[d] = -8.f * log1pf(expf(v)) * LOG2E;
    }
#pragma unroll
    for (int q = 0; q < 2; ++q) {
        int slot = q * 256 + tid;          // 0..511
        int lane = slot & 63;
        int fidx = slot >> 6;              // g*4 + fn*2 + kk2
        int g    = fidx >> 2;
        int fn   = (fidx >> 1) & 1;
        int kk2  = fidx & 1;
        int row = n32 * 32 + fn * 16 + (lane & 15);
        int col = kt * 64 + kk2 * 32 + ((lane >> 4) << 3);
        const float* src = (g ? w_a : w_in) + (size_t)h * BW_ * BW_;
        f16x8 v;
#pragma unroll
        for (int e = 0; e < 8; ++e)
            v[e] = (f16)src[(size_t)(col + e) * BW_ + row];
        size_t o = ((((size_t)(h * 16 + n32) * 8 + kt) * 8) + fidx) * 64 + lane;
        *(f16x8*)(wpk + o * 8) = v;
    }
}

// ---------- prep: x -> fp16 ----------
__global__ __launch_bounds__(256)
void prep_xh(const float* __restrict__ x, f16* __restrict__ xh) {
    size_t i = ((size_t)blockIdx.x * 256 + threadIdx.x) * 8;
    size_t stride = (size_t)gridDim.x * 256 * 8;
    for (; i < (size_t)M_ * D_; i += stride) {
        f32x4 v0 = *(const f32x4*)(x + i);
        f32x4 v1 = *(const f32x4*)(x + i + 4);
        f16x8 hv;
        hv[0] = (f16)v0.x; hv[1] = (f16)v0.y; hv[2] = (f16)v0.z; hv[3] = (f16)v0.w;
        hv[4] = (f16)v1.x; hv[5] = (f16)v1.y; hv[6] = (f16)v1.z; hv[7] = (f16)v1.w;
        *(f16x8*)(xh + i) = hv;
    }
}

// ---------- fused gate GEMM + epilogue + chunk-local scan ----------
// BM=128 (= one scan chunk), BN=64, BK=64, 4 waves (2x2), mfma 16x16x32 f16
// A via global_load_lds dbuf (16KB x2); B via pre-packed register fragments.
// Counted vmcnt(12). K-tiles permuted so tile covering cols [n0,n0+64) is
// LAST -> its LDS A-tile = epilogue xv. Scan decay stored as om = 1-a (f16):
// full relative precision where a~1 (the compounding regime).
#define BM 128
#define BN 64
#define BKK 64
#define NT (BW_/BKK)     // 8 K-tiles
#define BUFB 16384       // bytes per A staging buffer

// LDS map: staging buf0 @0, buf1 @16384 (32K).  Post-K-loop overlay:
//  om_s[128][66]f16 @0 (16896) | xn_s[128][66]f16 @16896 (16896)
//  segA[4][72]f32 @33792 | segY[4][72]f32 @34944 | rst_s[128]f32 @36096
#define SMEM_BYTES 36608

__global__ __launch_bounds__(256, 4)
void gemm_gates(const f16*   __restrict__ xh,
                const int*   __restrict__ segpos,
                const f16*   __restrict__ wpk,
                const float* __restrict__ b_in,
                const float* __restrict__ b_a,
                const float* __restrict__ msp2,
                f16x2* __restrict__ ylap,
                float* __restrict__ sumA,
                float* __restrict__ sumY) {
    __shared__ __align__(16) char smem[SMEM_BYTES];
    f16*   om_s = (f16*)smem;                 // [128][66]
    f16*   xn_s = (f16*)(smem + 16896);       // [128][66]
    float* segA = (float*)(smem + 33792);     // [4][72]
    float* segY = (float*)(smem + 34944);     // [4][72]
    float* rst_s= (float*)(smem + 36096);     // [128] (outside staging region)

    const int tid  = threadIdx.x;
    const int m0   = blockIdx.x * BM;
    const int n0   = blockIdx.y * BN;
    const int h    = blockIdx.z;
    const int lane = tid & 63;
    const int wid  = tid >> 6;
    const int wr   = wid >> 1;
    const int wc   = wid & 1;

    f32x4 accX[4][2] = {};
    f32x4 accA[4][2] = {};

    // reset flags -> LDS (region untouched by staging)
    if (tid < BM) rst_s[tid] = (segpos[m0 + tid] == 0) ? 1.f : 0.f;

    // A staging map (source col pre-swizzled; LDS dest linear — m173/m201)
    const int grow  = lane >> 3;
    const int gcolS = (((lane & 7) ^ grow) << 3);
    const f16* aSrc = xh + (size_t)(m0 + wid * 32 + grow) * D_ + h * BW_ + gcolS;

    // B packed fragment base for this wave: (h, n32 = n0/32 + wc)
    const f16* wbase = wpk + ((size_t)(h * 16) + (n0 >> 5) + wc) * 32768;

    const int swz  = (lane & 7) << 3;        // read-side XOR (involution)
    const int kx   = (lane >> 4) << 3;       // 0,8,16,24
    const int arow = wr * 64 + (lane & 15);

    const int rowb = wr * 64 + ((lane >> 4) << 2);
    const int txo = (n0 >> 6) + 1;   // permutation: tile (n0>>6) goes last

    f16x8 bfr[2][8];

    // prologue: stage permuted tile 0 (A -> buf0, B -> bfr[0])
    {
        const int k0 = (txo & (NT - 1)) * BKK;
        f16* Asb = (f16*)smem;
#pragma unroll
        for (int q = 0; q < 4; ++q)
            gl16(aSrc + k0 + (size_t)q * 8 * D_, &Asb[(wid * 32 + q * 8) * 64]);
        const f16* tp = wbase + (size_t)(txo & (NT - 1)) * 4096;
#pragma unroll
        for (int j = 0; j < 8; ++j)
            bfr[0][j] = *(const f16x8*)(tp + j * 512 + lane * 8);
    }

#pragma unroll
    for (int t = 0; t < NT; ++t) {
        const int cur = t & 1;
        if (t + 1 < NT) {
            const int kt1 = (t + 1 + txo) & (NT - 1);
            f16* Asb = (f16*)(smem + (cur ^ 1) * BUFB);
#pragma unroll
            for (int q = 0; q < 4; ++q)
                gl16(aSrc + kt1 * BKK + (size_t)q * 8 * D_, &Asb[(wid * 32 + q * 8) * 64]);
            const f16* tp = wbase + (size_t)kt1 * 4096;
#pragma unroll
            for (int j = 0; j < 8; ++j)
                bfr[cur ^ 1][j] = *(const f16x8*)(tp + j * 512 + lane * 8);
            asm volatile("s_waitcnt vmcnt(12)" ::: "memory");  // tile t landed
        } else {
            asm volatile("s_waitcnt vmcnt(0)" ::: "memory");
        }
        __builtin_amdgcn_s_barrier();          // all waves' A(t) visible
        __builtin_amdgcn_sched_barrier(0);

        const f16* Asb = (const f16*)(smem + cur * BUFB);
#pragma unroll
        for (int kk2 = 0; kk2 < 2; ++kk2) {
            const int kcolS = (kk2 * 32 + kx) ^ swz;
            f16x8 af[4];
#pragma unroll
            for (int fm = 0; fm < 4; ++fm)
                af[fm] = *(const f16x8*)&Asb[(arow + fm * 16) * 64 + kcolS];
#pragma unroll
            for (int fn = 0; fn < 2; ++fn) {
                f16x8 bx = bfr[cur][fn * 2 + kk2];
                f16x8 ba = bfr[cur][4 + fn * 2 + kk2];
#pragma unroll
                for (int fm = 0; fm < 4; ++fm) {
                    accX[fm][fn] = __builtin_amdgcn_mfma_f32_16x16x32_f16(af[fm], bx, accX[fm][fn], 0, 0, 0);
                    accA[fm][fn] = __builtin_amdgcn_mfma_f32_16x16x32_f16(af[fm], ba, accA[fm][fn], 0, 0, 0);
                }
            }
        }
        __builtin_amdgcn_sched_barrier(0);
        __builtin_amdgcn_s_barrier();          // reads done before overwrite
    }

    // ---- xv harvest: last tile (buf1) holds A cols [n0,n0+64) ----
    const f16* As1 = (const f16*)(smem + BUFB);
    f16 xvv[2][4][4];
#pragma unroll
    for (int fn = 0; fn < 2; ++fn) {
        const int ctile = wc * 32 + fn * 16 + (lane & 15);
#pragma unroll
        for (int fm = 0; fm < 4; ++fm)
#pragma unroll
            for (int reg = 0; reg < 4; ++reg) {
                const int rowt = rowb + fm * 16 + reg;
                xvv[fn][fm][reg] = As1[rowt * 64 + (ctile ^ ((rowt & 7) << 3))];
            }
    }
    __syncthreads();   // xv in regs before overlay writes

    // ---- pass A: epilogue math -> om = 1-a (f16) + xn (f16) in LDS ----
    // C/D layout: col = lane&15, row = (lane>>4)*4 + reg  [m89-verified]
    {
#pragma unroll
        for (int fn = 0; fn < 2; ++fn) {
            const int ctile = wc * 32 + fn * 16 + (lane & 15);
            const int d = h * BW_ + n0 + ctile;
            const float bx = b_in[d];
            const float ba = b_a[d];
            const float mspd = msp2[d];
#pragma unroll
            for (int fm = 0; fm < 4; ++fm) {
#pragma unroll
                for (int reg = 0; reg < 4; ++reg) {
                    const int rowt = rowb + fm * 16 + reg;       // 0..127
                    float gxl = accX[fm][fn][reg] + bx;
                    float gal = accA[fm][fn][reg] + ba;
                    float gx = __builtin_amdgcn_rcpf(1.f + __builtin_amdgcn_exp2f(-gxl * LOG2E));
                    float ga = __builtin_amdgcn_rcpf(1.f + __builtin_amdgcn_exp2f(-gal * LOG2E));
                    float a  = __builtin_amdgcn_exp2f(mspd * ga);
                    float a2 = a * a;                            // = exp(2*log_a)
                    float mult = __builtin_amdgcn_sqrtf(1.f + 1e-6f - a2);
                    float rv = rst_s[rowt];
                    a *= (1.f - rv);
                    mult = rv + (1.f - rv) * mult;
                    float xv = (float)xvv[fn][fm][reg];
                    om_s[rowt * 66 + ctile] = (f16)(1.f - a);
                    xn_s[rowt * 66 + ctile] = (f16)(xv * gx * mult);
                }
            }
        }
    }
    __syncthreads();

    // ---- pass B: per-segment (32-step) summaries ----
    const int scol = tid & 63;
    const int sseg = tid >> 6;
    {
        float A = 1.f, yv = 0.f;
#pragma unroll 4
        for (int t = sseg * 32; t < sseg * 32 + 32; ++t) {
            float a  = 1.f - (float)om_s[t * 66 + scol];
            float xn = (float)xn_s[t * 66 + scol];
            yv = fmaf(a, yv, xn);
            A *= a;
        }
        segA[sseg * 72 + scol] = A;
        segY[sseg * 72 + scol] = yv;
    }
    __syncthreads();

    // ---- pass C: carry-in per segment, rewalk, write packed (yloc, apfx) ----
    {
        float cy = 0.f, pA = 1.f;
        for (int s = 0; s < sseg; ++s) {
            float As_ = segA[s * 72 + scol];
            float Ys_ = segY[s * 72 + scol];
            cy = fmaf(As_, cy, Ys_);
            pA *= As_;
        }
        float Arun = 1.f, yv = cy;
        const size_t obase = (size_t)(m0 + sseg * 32) * D_ + h * BW_ + n0 + scol;
#pragma unroll 4
        for (int i = 0; i < 32; ++i) {
            const int t = sseg * 32 + i;
            float a  = 1.f - (float)om_s[t * 66 + scol];
            float xn = (float)xn_s[t * 66 + scol];
            yv = fmaf(a, yv, xn);
            Arun *= a;
            f16x2 p;
            p[0] = (f16)yv;
            p[1] = (f16)(pA * Arun);
            ylap[obase + (size_t)i * D_] = p;
        }
        if (sseg == 3) {
            const int bb = m0 >> 11;             // batch
            const int cc = (m0 & 2047) >> 7;     // chunk in batch
            size_t si = ((size_t)bb * NCH + cc) * D_ + h * BW_ + n0 + scol;
            sumA[si] = pA * Arun;
            sumY[si] = yv;
        }
    }
}

// ---------- scan phase 2: scan over chunk summaries -> carry-in per chunk ----------
__global__ __launch_bounds__(256)
void scan_mid(const float* __restrict__ sumA, const float* __restrict__ sumY,
              float* __restrict__ carry) {
    int d = blockIdx.x * 256 + threadIdx.x;
    int b = blockIdx.y;
    float hcur = 0.f;
#pragma unroll
    for (int c = 0; c < NCH; ++c) {
        size_t si = ((size_t)b * NCH + c) * D_ + d;
        carry[si] = hcur;
        hcur = fmaf(sumA[si], hcur, sumY[si]);
    }
}

// ---------- scan phase 3: elementwise y = yloc + carry * apfx ----------
__global__ __launch_bounds__(256)
void scan_apply(const float* __restrict__ carry, const f16x2* __restrict__ ylap,
                float* __restrict__ y) {
    size_t i4 = (size_t)blockIdx.x * 256 + threadIdx.x;
    const size_t stride = (size_t)gridDim.x * 256;
    const size_t n4 = (size_t)M_ * D_ / 4;
    for (; i4 < n4; i4 += stride) {
        size_t i = i4 * 4;
        size_t row = i >> 12;
        int d = (int)(i & 4095);
        int b = (int)(row >> 11);
        int c = ((int)row & 2047) >> 7;
        const float* cp = carry + (((size_t)(b * NCH + c)) << 12) + d;
        f32x4 cv = *(const f32x4*)cp;
        f16x8 pk = *(const f16x8*)(ylap + i);   // [y0,a0,y1,a1,y2,a2,y3,a3]
        f32x4 o;
        o.x = fmaf(cv.x, (float)pk[1], (float)pk[0]);
        o.y = fmaf(cv.y, (float)pk[3], (float)pk[2]);
        o.z = fmaf(cv.z, (float)pk[5], (float)pk[4]);
        o.w = fmaf(cv.w, (float)pk[7], (float)pk[6]);
        *(f32x4*)(y + i) = o;
    }
}

extern "C" void kernel_launch(void* const* d_in, const int* in_sizes, int n_in,
                              void* d_out, int out_size, void* d_ws, size_t ws_size,
                              hipStream_t stream) {
    const float* x       = (const float*)d_in[0];
    const int*   segpos  = (const int*)d_in[1];
    // d_in[2] = prev_h (unused by reference for L>1 path)
    const float* w_in    = (const float*)d_in[3];
    const float* b_in    = (const float*)d_in[4];
    const float* w_a     = (const float*)d_in[5];
    const float* b_a     = (const float*)d_in[6];
    const float* a_param = (const float*)d_in[7];

    float* y  = (float*)d_out;
    char*  ws = (char*)d_ws;
    f16*   wpk   = (f16*)(ws + OFF_WPK);
    float* msp2  = (float*)(ws + OFF_MSP);
    f16*   xh    = (f16*)(ws + OFF_XH);
    f16x2* ylap  = (f16x2*)(ws + OFF_YLAP);
    float* sumA  = (float*)(ws + OFF_SUMA);
    float* sumY  = (float*)(ws + OFF_SUMY);
    float* carry = (float*)(ws + OFF_CARRY);

    prep_wpack<<<dim3(1024), 256, 0, stream>>>(w_in, w_a, a_param, wpk, msp2);
    prep_xh<<<dim3(2048), 256, 0, stream>>>(x, xh);
    gemm_gates<<<dim3(M_ / BM, BW_ / BN, H_), 256, 0, stream>>>(
        xh, segpos, wpk, b_in, b_a, msp2, ylap, sumA, sumY);
    scan_mid<<<dim3(D_ / 256, B_), 256, 0, stream>>>(sumA, sumY, carry);
    scan_apply<<<dim3(4096), 256, 0, stream>>>(carry, ylap, y);
}

// Round 9
// 219.248 us; speedup vs baseline: 2.2048x; 2.0403x over previous
//
#include <hip/hip_runtime.h>
#include <hip/hip_bf16.h>

typedef _Float16 f16;
typedef _Float16 f16x2 __attribute__((ext_vector_type(2)));
typedef _Float16 f16x4 __attribute__((ext_vector_type(4)));
typedef _Float16 f16x8 __attribute__((ext_vector_type(8)));
typedef float f32x4 __attribute__((ext_vector_type(4)));

#define B_  4
#define L_  2048
#define D_  4096
#define H_  8
#define BW_ 512
#define M_  (B_*L_)      // 8192
#define CHUNK 128
#define NCH (L_/CHUNK)   // 16
#define LOG2E 1.4426950408889634f

// workspace layout (bytes)
static const size_t OFF_WPK   = 0;                 // packed B frags: 8MB (both gates)
static const size_t OFF_MSP   = 8ull<<20;          // D_ f32 (16KB), pre-scaled by log2e
static const size_t OFF_XH    = 9ull<<20;          // M*D fp16 = 64MB
static const size_t OFF_YLAP  = 73ull<<20;         // M*D f16x2 (yloc,apfx) = 134MB
static const size_t OFF_SUMA  = 208ull<<20;        // B*NCH*D f32 = 1MB
static const size_t OFF_SUMY  = 209ull<<20;
static const size_t OFF_CARRY = 210ull<<20;

__device__ __forceinline__ void gl16(const void* g, void* l) {
    __builtin_amdgcn_global_load_lds(
        (const __attribute__((address_space(1))) unsigned int*)g,
        (__attribute__((address_space(3))) unsigned int*)l, 16, 0, 0);
}

// ---------- prep: pack W^T into MFMA B-fragment order (+ msp2) ----------
// layout: wpk[((h*16 + n32)*8 + kt)*8 + fidx][lane] : f16x8
//   fidx = g*4 + fn*2 + kk2 ; fragment element e:
//   B[n = n32*32 + fn*16 + (lane&15)][k = kt*64 + kk2*32 + (lane>>4)*8 + e]
//   where B[n][k] = w[h][k][n]
__global__ __launch_bounds__(256)
void prep_wpack(const float* __restrict__ w_in, const float* __restrict__ w_a,
                const float* __restrict__ a_param,
                f16* __restrict__ wpk, float* __restrict__ msp2) {
    const int kt  = blockIdx.x & 7;
    const int n32 = (blockIdx.x >> 3) & 15;
    const int h   = blockIdx.x >> 7;
    const int tid = threadIdx.x;
    if (blockIdx.x < 16) {                 // folded: msp2[d]
        int d = blockIdx.x * 256 + tid;
        float v = a_param[d];
        msp2[d] = -8.f * log1pf(expf(v)) * LOG2E;
    }
#pragma unroll
    for (int q = 0; q < 2; ++q) {
        int slot = q * 256 + tid;          // 0..511
        int lane = slot & 63;
        int fidx = slot >> 6;              // g*4 + fn*2 + kk2
        int g    = fidx >> 2;
        int fn   = (fidx >> 1) & 1;
        int kk2  = fidx & 1;
        int row = n32 * 32 + fn * 16 + (lane & 15);
        int col = kt * 64 + kk2 * 32 + ((lane >> 4) << 3);
        const float* src = (g ? w_a : w_in) + (size_t)h * BW_ * BW_;
        f16x8 v;
#pragma unroll
        for (int e = 0; e < 8; ++e)
            v[e] = (f16)src[(size_t)(col + e) * BW_ + row];
        size_t o = ((((size_t)(h * 16 + n32) * 8 + kt) * 8) + fidx) * 64 + lane;
        *(f16x8*)(wpk + o * 8) = v;
    }
}

// ---------- prep: x -> fp16 ----------
__global__ __launch_bounds__(256)
void prep_xh(const float* __restrict__ x, f16* __restrict__ xh) {
    size_t i = ((size_t)blockIdx.x * 256 + threadIdx.x) * 8;
    size_t stride = (size_t)gridDim.x * 256 * 8;
    for (; i < (size_t)M_ * D_; i += stride) {
        f32x4 v0 = *(const f32x4*)(x + i);
        f32x4 v1 = *(const f32x4*)(x + i + 4);
        f16x8 hv;
        hv[0] = (f16)v0.x; hv[1] = (f16)v0.y; hv[2] = (f16)v0.z; hv[3] = (f16)v0.w;
        hv[4] = (f16)v1.x; hv[5] = (f16)v1.y; hv[6] = (f16)v1.z; hv[7] = (f16)v1.w;
        *(f16x8*)(xh + i) = hv;
    }
}

// ---------- fused gate GEMM + epilogue + chunk-local scan ----------
// BM=128 (= one scan chunk), BN=64, BK=64, 4 waves (2x2), mfma 16x16x32 f16
// A via global_load_lds dbuf (16KB x2); B via pre-packed register fragments.
// Counted vmcnt(12). K-tiles permuted so tile covering cols [n0,n0+64) is
// LAST -> its LDS A-tile = epilogue xv. Scan decay stored as om = 1-a (f16).
// LDS 36.9KB + ~116 total regs -> 4 blocks/CU without forcing the allocator
// (R8's (256,4) bound caused scratch spill: WRITE 874MB, gemm 349us).
#define BM 128
#define BN 64
#define BKK 64
#define NT (BW_/BKK)     // 8 K-tiles
#define BUFB 16384       // bytes per A staging buffer

// LDS map: staging buf0 @0, buf1 @16384 (32K).  Post-K-loop overlay:
//  om_s[128][66]f16 @0 (16896) | xn_s[128][66]f16 @16896 (16896)
//  segA[4][72]f32 @33792 | segY[4][72]f32 @34944 | rst_s[128]f32 @36096
#define SMEM_BYTES 36608

__global__ __launch_bounds__(256, 3)
void gemm_gates(const f16*   __restrict__ xh,
                const int*   __restrict__ segpos,
                const f16*   __restrict__ wpk,
                const float* __restrict__ b_in,
                const float* __restrict__ b_a,
                const float* __restrict__ msp2,
                f16x2* __restrict__ ylap,
                float* __restrict__ sumA,
                float* __restrict__ sumY) {
    __shared__ __align__(16) char smem[SMEM_BYTES];
    f16*   om_s = (f16*)smem;                 // [128][66]
    f16*   xn_s = (f16*)(smem + 16896);       // [128][66]
    float* segA = (float*)(smem + 33792);     // [4][72]
    float* segY = (float*)(smem + 34944);     // [4][72]
    float* rst_s= (float*)(smem + 36096);     // [128] (outside staging region)

    const int tid  = threadIdx.x;
    const int m0   = blockIdx.x * BM;
    const int n0   = blockIdx.y * BN;
    const int h    = blockIdx.z;
    const int lane = tid & 63;
    const int wid  = tid >> 6;
    const int wr   = wid >> 1;
    const int wc   = wid & 1;

    f32x4 accX[4][2] = {};
    f32x4 accA[4][2] = {};

    // reset flags -> LDS (region untouched by staging)
    if (tid < BM) rst_s[tid] = (segpos[m0 + tid] == 0) ? 1.f : 0.f;

    // A staging map (source col pre-swizzled; LDS dest linear — m173/m201)
    const int grow  = lane >> 3;
    const int gcolS = (((lane & 7) ^ grow) << 3);
    const f16* aSrc = xh + (size_t)(m0 + wid * 32 + grow) * D_ + h * BW_ + gcolS;

    // B packed fragment base for this wave: (h, n32 = n0/32 + wc)
    const f16* wbase = wpk + ((size_t)(h * 16) + (n0 >> 5) + wc) * 32768;

    const int swz  = (lane & 7) << 3;        // read-side XOR (involution)
    const int kx   = (lane >> 4) << 3;       // 0,8,16,24
    const int arow = wr * 64 + (lane & 15);

    const int rowb = wr * 64 + ((lane >> 4) << 2);
    const int txo = (n0 >> 6) + 1;   // permutation: tile (n0>>6) goes last

    f16x8 bfr[2][8];

    // prologue: stage permuted tile 0 (A -> buf0, B -> bfr[0])
    {
        const int k0 = (txo & (NT - 1)) * BKK;
        f16* Asb = (f16*)smem;
#pragma unroll
        for (int q = 0; q < 4; ++q)
            gl16(aSrc + k0 + (size_t)q * 8 * D_, &Asb[(wid * 32 + q * 8) * 64]);
        const f16* tp = wbase + (size_t)(txo & (NT - 1)) * 4096;
#pragma unroll
        for (int j = 0; j < 8; ++j)
            bfr[0][j] = *(const f16x8*)(tp + j * 512 + lane * 8);
    }

#pragma unroll
    for (int t = 0; t < NT; ++t) {
        const int cur = t & 1;
        if (t + 1 < NT) {
            const int kt1 = (t + 1 + txo) & (NT - 1);
            f16* Asb = (f16*)(smem + (cur ^ 1) * BUFB);
#pragma unroll
            for (int q = 0; q < 4; ++q)
                gl16(aSrc + kt1 * BKK + (size_t)q * 8 * D_, &Asb[(wid * 32 + q * 8) * 64]);
            const f16* tp = wbase + (size_t)kt1 * 4096;
#pragma unroll
            for (int j = 0; j < 8; ++j)
                bfr[cur ^ 1][j] = *(const f16x8*)(tp + j * 512 + lane * 8);
            asm volatile("s_waitcnt vmcnt(12)" ::: "memory");  // tile t landed
        } else {
            asm volatile("s_waitcnt vmcnt(0)" ::: "memory");
        }
        __builtin_amdgcn_s_barrier();          // all waves' A(t) visible
        __builtin_amdgcn_sched_barrier(0);

        const f16* Asb = (const f16*)(smem + cur * BUFB);
#pragma unroll
        for (int kk2 = 0; kk2 < 2; ++kk2) {
            const int kcolS = (kk2 * 32 + kx) ^ swz;
            f16x8 af[4];
#pragma unroll
            for (int fm = 0; fm < 4; ++fm)
                af[fm] = *(const f16x8*)&Asb[(arow + fm * 16) * 64 + kcolS];
#pragma unroll
            for (int fn = 0; fn < 2; ++fn) {
                f16x8 bx = bfr[cur][fn * 2 + kk2];
                f16x8 ba = bfr[cur][4 + fn * 2 + kk2];
#pragma unroll
                for (int fm = 0; fm < 4; ++fm) {
                    accX[fm][fn] = __builtin_amdgcn_mfma_f32_16x16x32_f16(af[fm], bx, accX[fm][fn], 0, 0, 0);
                    accA[fm][fn] = __builtin_amdgcn_mfma_f32_16x16x32_f16(af[fm], ba, accA[fm][fn], 0, 0, 0);
                }
            }
        }
        __builtin_amdgcn_sched_barrier(0);
        __builtin_amdgcn_s_barrier();          // reads done before overwrite
    }

    // ---- xv harvest: last tile (buf1) holds A cols [n0,n0+64) ----
    const f16* As1 = (const f16*)(smem + BUFB);
    f16 xvv[2][4][4];
#pragma unroll
    for (int fn = 0; fn < 2; ++fn) {
        const int ctile = wc * 32 + fn * 16 + (lane & 15);
#pragma unroll
        for (int fm = 0; fm < 4; ++fm)
#pragma unroll
            for (int reg = 0; reg < 4; ++reg) {
                const int rowt = rowb + fm * 16 + reg;
                xvv[fn][fm][reg] = As1[rowt * 64 + (ctile ^ ((rowt & 7) << 3))];
            }
    }
    __syncthreads();   // xv in regs before overlay writes

    // ---- pass A: epilogue math -> om = 1-a (f16) + xn (f16) in LDS ----
    // C/D layout: col = lane&15, row = (lane>>4)*4 + reg  [m89-verified]
    {
#pragma unroll
        for (int fn = 0; fn < 2; ++fn) {
            const int ctile = wc * 32 + fn * 16 + (lane & 15);
            const int d = h * BW_ + n0 + ctile;
            const float bx = b_in[d];
            const float ba = b_a[d];
            const float mspd = msp2[d];
#pragma unroll
            for (int fm = 0; fm < 4; ++fm) {
#pragma unroll
                for (int reg = 0; reg < 4; ++reg) {
                    const int rowt = rowb + fm * 16 + reg;       // 0..127
                    float gxl = accX[fm][fn][reg] + bx;
                    float gal = accA[fm][fn][reg] + ba;
                    float gx = __builtin_amdgcn_rcpf(1.f + __builtin_amdgcn_exp2f(-gxl * LOG2E));
                    float ga = __builtin_amdgcn_rcpf(1.f + __builtin_amdgcn_exp2f(-gal * LOG2E));
                    float a  = __builtin_amdgcn_exp2f(mspd * ga);
                    float a2 = a * a;                            // = exp(2*log_a)
                    float mult = __builtin_amdgcn_sqrtf(1.f + 1e-6f - a2);
                    float rv = rst_s[rowt];
                    a *= (1.f - rv);
                    mult = rv + (1.f - rv) * mult;
                    float xv = (float)xvv[fn][fm][reg];
                    om_s[rowt * 66 + ctile] = (f16)(1.f - a);
                    xn_s[rowt * 66 + ctile] = (f16)(xv * gx * mult);
                }
            }
        }
    }
    __syncthreads();

    // ---- pass B: per-segment (32-step) summaries ----
    const int scol = tid & 63;
    const int sseg = tid >> 6;
    {
        float A = 1.f, yv = 0.f;
#pragma unroll 4
        for (int t = sseg * 32; t < sseg * 32 + 32; ++t) {
            float a  = 1.f - (float)om_s[t * 66 + scol];
            float xn = (float)xn_s[t * 66 + scol];
            yv = fmaf(a, yv, xn);
            A *= a;
        }
        segA[sseg * 72 + scol] = A;
        segY[sseg * 72 + scol] = yv;
    }
    __syncthreads();

    // ---- pass C: carry-in per segment, rewalk, write packed (yloc, apfx) ----
    {
        float cy = 0.f, pA = 1.f;
        for (int s = 0; s < sseg; ++s) {
            float As_ = segA[s * 72 + scol];
            float Ys_ = segY[s * 72 + scol];
            cy = fmaf(As_, cy, Ys_);
            pA *= As_;
        }
        float Arun = 1.f, yv = cy;
        const size_t obase = (size_t)(m0 + sseg * 32) * D_ + h * BW_ + n0 + scol;
#pragma unroll 4
        for (int i = 0; i < 32; ++i) {
            const int t = sseg * 32 + i;
            float a  = 1.f - (float)om_s[t * 66 + scol];
            float xn = (float)xn_s[t * 66 + scol];
            yv = fmaf(a, yv, xn);
            Arun *= a;
            f16x2 p;
            p[0] = (f16)yv;
            p[1] = (f16)(pA * Arun);
            ylap[obase + (size_t)i * D_] = p;
        }
        if (sseg == 3) {
            const int bb = m0 >> 11;             // batch
            const int cc = (m0 & 2047) >> 7;     // chunk in batch
            size_t si = ((size_t)bb * NCH + cc) * D_ + h * BW_ + n0 + scol;
            sumA[si] = pA * Arun;
            sumY[si] = yv;
        }
    }
}

// ---------- scan phase 2: scan over chunk summaries -> carry-in per chunk ----------
__global__ __launch_bounds__(256)
void scan_mid(const float* __restrict__ sumA, const float* __restrict__ sumY,
              float* __restrict__ carry) {
    int d = blockIdx.x * 256 + threadIdx.x;
    int b = blockIdx.y;
    float hcur = 0.f;
#pragma unroll
    for (int c = 0; c < NCH; ++c) {
        size_t si = ((size_t)b * NCH + c) * D_ + d;
        carry[si] = hcur;
        hcur = fmaf(sumA[si], hcur, sumY[si]);
    }
}

// ---------- scan phase 3: elementwise y = yloc + carry * apfx ----------
__global__ __launch_bounds__(256)
void scan_apply(const float* __restrict__ carry, const f16x2* __restrict__ ylap,
                float* __restrict__ y) {
    size_t i4 = (size_t)blockIdx.x * 256 + threadIdx.x;
    const size_t stride = (size_t)gridDim.x * 256;
    const size_t n4 = (size_t)M_ * D_ / 4;
    for (; i4 < n4; i4 += stride) {
        size_t i = i4 * 4;
        size_t row = i >> 12;
        int d = (int)(i & 4095);
        int b = (int)(row >> 11);
        int c = ((int)row & 2047) >> 7;
        const float* cp = carry + (((size_t)(b * NCH + c)) << 12) + d;
        f32x4 cv = *(const f32x4*)cp;
        f16x8 pk = *(const f16x8*)(ylap + i);   // [y0,a0,y1,a1,y2,a2,y3,a3]
        f32x4 o;
        o.x = fmaf(cv.x, (float)pk[1], (float)pk[0]);
        o.y = fmaf(cv.y, (float)pk[3], (float)pk[2]);
        o.z = fmaf(cv.z, (float)pk[5], (float)pk[4]);
        o.w = fmaf(cv.w, (float)pk[7], (float)pk[6]);
        *(f32x4*)(y + i) = o;
    }
}

extern "C" void kernel_launch(void* const* d_in, const int* in_sizes, int n_in,
                              void* d_out, int out_size, void* d_ws, size_t ws_size,
                              hipStream_t stream) {
    const float* x       = (const float*)d_in[0];
    const int*   segpos  = (const int*)d_in[1];
    // d_in[2] = prev_h (unused by reference for L>1 path)
    const float* w_in    = (const float*)d_in[3];
    const float* b_in    = (const float*)d_in[4];
    const float* w_a     = (const float*)d_in[5];
    const float* b_a     = (const float*)d_in[6];
    const float* a_param = (const float*)d_in[7];

    float* y  = (float*)d_out;
    char*  ws = (char*)d_ws;
    f16*   wpk   = (f16*)(ws + OFF_WPK);
    float* msp2  = (float*)(ws + OFF_MSP);
    f16*   xh    = (f16*)(ws + OFF_XH);
    f16x2* ylap  = (f16x2*)(ws + OFF_YLAP);
    float* sumA  = (float*)(ws + OFF_SUMA);
    float* sumY  = (float*)(ws + OFF_SUMY);
    float* carry = (float*)(ws + OFF_CARRY);

    prep_wpack<<<dim3(1024), 256, 0, stream>>>(w_in, w_a, a_param, wpk, msp2);
    prep_xh<<<dim3(2048), 256, 0, stream>>>(x, xh);
    gemm_gates<<<dim3(M_ / BM, BW_ / BN, H_), 256, 0, stream>>>(
        xh, segpos, wpk, b_in, b_a, msp2, ylap, sumA, sumY);
    scan_mid<<<dim3(D_ / 256, B_), 256, 0, stream>>>(sumA, sumY, carry);
    scan_apply<<<dim3(4096), 256, 0, stream>>>(carry, ylap, y);
}